// Round 6
// baseline (286.016 us; speedup 1.0000x reference)
//
#include <hip/hip_runtime.h>

#define N_NODES 100000
#define E_EDGES 3200000
#define IN_CH 256
#define HID 32
#define OUT_CH 16

#define B_BUCKETS 250     // buckets over nodes
#define NPB 400           // nodes per bucket (250*400 = 100000 exactly)
#define CAP 20000         // LDS staging capacity in k_bsort
#define PART_BLOCKS 512
#define PART_CHUNK ((E_EDGES + PART_BLOCKS - 1) / PART_BLOCKS)  // 6250

typedef unsigned short u16;

__device__ __forceinline__ unsigned bf16rtn(float f) {
    unsigned u = __float_as_uint(f);
    return (u + 0x7FFFu + ((u >> 16) & 1u)) >> 16;   // round-to-nearest-even, finite inputs
}
__device__ __forceinline__ float bflo(unsigned u) { return __uint_as_float(u << 16); }
__device__ __forceinline__ float bfhi(unsigned u) { return __uint_as_float(u & 0xFFFF0000u); }

// ---------------- phase 1: per-bucket edge counts ----------------

__global__ void k_bcount(const int* __restrict__ col, int* __restrict__ bcnt, int e) {
    __shared__ int h[B_BUCKETS];
    for (int i = threadIdx.x; i < B_BUCKETS; i += blockDim.x) h[i] = 0;
    __syncthreads();
    for (int i = blockIdx.x * blockDim.x + threadIdx.x; i < e; i += gridDim.x * blockDim.x)
        atomicAdd(&h[col[i] / NPB], 1);
    __syncthreads();
    for (int i = threadIdx.x; i < B_BUCKETS; i += blockDim.x)
        if (h[i]) atomicAdd(&bcnt[i], h[i]);
}

// ---------------- phase 2: scan bucket counts (1 block) ----------------

__global__ void k_bscan(const int* __restrict__ bcnt, int* __restrict__ bstart,
                        int* __restrict__ bcur) {
    __shared__ int a[256], b[256];
    int t = threadIdx.x;
    int myc = (t < B_BUCKETS) ? bcnt[t] : 0;
    a[t] = myc;
    __syncthreads();
    int* sp = a; int* dp = b;
    for (int off = 1; off < 256; off <<= 1) {
        dp[t] = sp[t] + ((t >= off) ? sp[t - off] : 0);
        __syncthreads();
        int* tm = sp; sp = dp; dp = tm;
    }
    int incl = sp[t];
    int excl = incl - myc;
    if (t < B_BUCKETS) { bstart[t] = excl; bcur[t] = excl; }
    if (t == B_BUCKETS - 1) bstart[B_BUCKETS] = incl;
}

// ---------------- phase 3: partition edges into buckets (LDS-aggregated) ----------------

__global__ __launch_bounds__(256) void k_part(const int* __restrict__ row,
                                              const int* __restrict__ col,
                                              int* __restrict__ bcur,
                                              unsigned* __restrict__ psrc, int e) {
    __shared__ int hist[B_BUCKETS];
    __shared__ int base[B_BUCKETS];
    int lo = blockIdx.x * PART_CHUNK;
    int hi = min(e, lo + PART_CHUNK);
    if (lo >= hi) return;
    for (int i = threadIdx.x; i < B_BUCKETS; i += blockDim.x) hist[i] = 0;
    __syncthreads();
    for (int i = lo + threadIdx.x; i < hi; i += blockDim.x)
        atomicAdd(&hist[col[i] / NPB], 1);
    __syncthreads();
    for (int i = threadIdx.x; i < B_BUCKETS; i += blockDim.x) {
        int h = hist[i];
        base[i] = h ? atomicAdd(&bcur[i], h) : 0;
    }
    __syncthreads();
    for (int i = threadIdx.x; i < B_BUCKETS; i += blockDim.x) hist[i] = 0; // reuse as cursor
    __syncthreads();
    for (int i = lo + threadIdx.x; i < hi; i += blockDim.x) {
        int c = col[i];
        int b = c / NPB;
        int pos = base[b] + atomicAdd(&hist[b], 1);
        psrc[pos] = ((unsigned)(c - b * NPB) << 17) | (unsigned)row[i];
    }
}

// ---------------- phase 4: within-bucket sort in LDS -> srow, deg, start, dis ----------------

__global__ __launch_bounds__(512) void k_bsort(const unsigned* __restrict__ psrc,
                                               const int* __restrict__ bstart,
                                               int* __restrict__ srow, int* __restrict__ deg,
                                               int* __restrict__ start, float* __restrict__ dis) {
    __shared__ unsigned buf[CAP];
    __shared__ int cnt[512];
    __shared__ int sa[512];
    __shared__ int sb[512];
    int b = blockIdx.x, t = threadIdx.x;
    int s0 = bstart[b], s1 = bstart[b + 1], len = s1 - s0;

    cnt[t] = 0;
    __syncthreads();
    for (int i = t; i < len; i += 512)
        atomicAdd(&cnt[psrc[s0 + i] >> 17], 1);
    __syncthreads();

    sa[t] = cnt[t];
    __syncthreads();
    int* sp = sa; int* dp = sb;
    for (int off = 1; off < 512; off <<= 1) {
        dp[t] = sp[t] + ((t >= off) ? sp[t - off] : 0);
        __syncthreads();
        int* tm = sp; sp = dp; dp = tm;
    }
    int ex = sp[t] - cnt[t];
    __syncthreads();
    sa[t] = ex;
    sb[t] = ex;
    if (t < NPB) {
        int node = b * NPB + t;
        int d = cnt[t];
        deg[node] = d;
        start[node] = s0 + ex;
        dis[node] = rsqrtf((float)(d + 1));
    }
    __syncthreads();

    bool fits = (len <= CAP);
    for (int i = t; i < len; i += 512) {
        unsigned p = psrc[s0 + i];
        int cl = (int)(p >> 17);
        int pos = atomicAdd(&sb[cl], 1);
        if (fits) buf[pos] = p & 0x1FFFFu;
        else      srow[s0 + pos] = (int)(p & 0x1FFFFu);
    }
    __syncthreads();
    if (fits)
        for (int i = t; i < len; i += 512)
            srow[s0 + i] = (int)buf[i];
}

// ---------------- layer 1 GEMM: h0sh = bf16( dis * (x @ W1) ), LDS-staged ----------------

#define G1_NODES 64
#define G1_KC 64
#define G1_NCHUNK (IN_CH / G1_KC)   // 4

__global__ __launch_bounds__(256) void k_gemm1(const float* __restrict__ x,
                                               const float* __restrict__ W1,
                                               const float* __restrict__ dis,
                                               u16* __restrict__ h0sh, int n) {
    __shared__ float lds[3 * G1_NODES * 33];
    float (*xt)[G1_NODES + 1] = (float (*)[G1_NODES + 1])lds;

    int tid = threadIdx.x;
    int wv = __builtin_amdgcn_readfirstlane(tid >> 6);
    int lane = tid & 63;
    int vbase = blockIdx.x * G1_NODES;

    float4 g[4];
#pragma unroll
    for (int it = 0; it < 4; ++it) {
        int f = it * 256 + tid;
        int nl = f >> 4, q = f & 15;
        int v = vbase + nl; if (v >= n) v = n - 1;
        g[it] = *reinterpret_cast<const float4*>(x + (size_t)v * IN_CH + q * 4);
    }

    float acc[HID];
#pragma unroll
    for (int c = 0; c < HID; ++c) acc[c] = 0.f;

    for (int ch = 0; ch < G1_NCHUNK; ++ch) {
        __syncthreads();
#pragma unroll
        for (int it = 0; it < 4; ++it) {
            int f = it * 256 + tid;
            int nl = f >> 4, q = f & 15;
            xt[q * 4 + 0][nl] = g[it].x;
            xt[q * 4 + 1][nl] = g[it].y;
            xt[q * 4 + 2][nl] = g[it].z;
            xt[q * 4 + 3][nl] = g[it].w;
        }
        __syncthreads();
        if (ch + 1 < G1_NCHUNK) {
#pragma unroll
            for (int it = 0; it < 4; ++it) {
                int f = it * 256 + tid;
                int nl = f >> 4, q = f & 15;
                int v = vbase + nl; if (v >= n) v = n - 1;
                g[it] = *reinterpret_cast<const float4*>(
                    x + (size_t)v * IN_CH + (ch + 1) * G1_KC + q * 4);
            }
        }
#pragma unroll
        for (int j = 0; j < 16; ++j) {
            int kk = ch * G1_KC + wv * 16 + j;
            float xs = xt[wv * 16 + j][lane];
            const float* wrow = W1 + kk * HID;
#pragma unroll
            for (int c = 0; c < HID; ++c)
                acc[c] = fmaf(xs, wrow[c], acc[c]);
        }
    }

    __syncthreads();
    if (wv > 0) {
        float* dst = lds + (wv - 1) * (G1_NODES * 33) + lane * 33;
#pragma unroll
        for (int c = 0; c < HID; ++c) dst[c] = acc[c];
    }
    __syncthreads();
    if (wv == 0) {
        int v = vbase + lane;
        if (v < n) {
#pragma unroll
            for (int p = 0; p < 3; ++p) {
                const float* srcp = lds + p * (G1_NODES * 33) + lane * 33;
#pragma unroll
                for (int c = 0; c < HID; ++c) acc[c] += srcp[c];
            }
            float dv = dis[v];
            uint4* o4 = reinterpret_cast<uint4*>(h0sh + (size_t)v * HID);
#pragma unroll
            for (int qq = 0; qq < 4; ++qq) {
                unsigned p0 = bf16rtn(acc[qq * 8 + 0] * dv) | (bf16rtn(acc[qq * 8 + 1] * dv) << 16);
                unsigned p1 = bf16rtn(acc[qq * 8 + 2] * dv) | (bf16rtn(acc[qq * 8 + 3] * dv) << 16);
                unsigned p2 = bf16rtn(acc[qq * 8 + 4] * dv) | (bf16rtn(acc[qq * 8 + 5] * dv) << 16);
                unsigned p3 = bf16rtn(acc[qq * 8 + 6] * dv) | (bf16rtn(acc[qq * 8 + 7] * dv) << 16);
                o4[qq] = make_uint4(p0, p1, p2, p3);
            }
        }
    }
}

// ---------------- aggregation 1: hsh = bf16( dis * relu(dv*(sum h0s_u + h0s_v) + b1) ) ----------------
// 16 dests/wave, 4 lanes/dest, lane covers 8 channels (16 B bf16 gather), unroll 4.

__global__ __launch_bounds__(256) void k_agg1(const u16* __restrict__ h0sh,
                                              const int* __restrict__ srow,
                                              const int* __restrict__ start,
                                              const int* __restrict__ deg,
                                              const float* __restrict__ dis,
                                              const float* __restrict__ b1,
                                              u16* __restrict__ hsh, int n) {
    int tid = threadIdx.x;
    int lane = tid & 63;
    int g = lane >> 2;          // dest within wave, 0..15
    int q = lane & 3;           // channel-octet, 0..3
    int wv = tid >> 6;
    int v = blockIdx.x * 64 + wv * 16 + g;
    if (v >= n) v = n - 1;
    int s = start[v], d = deg[v];
    float dv = dis[v];

    float acc[8];
#pragma unroll
    for (int c = 0; c < 8; ++c) acc[c] = 0.f;

    for (int i = 0; i < d; i += 4) {
#pragma unroll
        for (int j = 0; j < 4; ++j) {
            int idx = i + j;
            bool valid = idx < d;
            int u = srow[s + (valid ? idx : 0)];
            uint4 gv = *reinterpret_cast<const uint4*>(h0sh + (size_t)u * HID + q * 8);
            float m = valid ? 1.f : 0.f;
            acc[0] = fmaf(m, bflo(gv.x), acc[0]);
            acc[1] = fmaf(m, bfhi(gv.x), acc[1]);
            acc[2] = fmaf(m, bflo(gv.y), acc[2]);
            acc[3] = fmaf(m, bfhi(gv.y), acc[3]);
            acc[4] = fmaf(m, bflo(gv.z), acc[4]);
            acc[5] = fmaf(m, bfhi(gv.z), acc[5]);
            acc[6] = fmaf(m, bflo(gv.w), acc[6]);
            acc[7] = fmaf(m, bfhi(gv.w), acc[7]);
        }
    }

    uint4 sv = *reinterpret_cast<const uint4*>(h0sh + (size_t)v * HID + q * 8);
    float self[8] = {bflo(sv.x), bfhi(sv.x), bflo(sv.y), bfhi(sv.y),
                     bflo(sv.z), bfhi(sv.z), bflo(sv.w), bfhi(sv.w)};
    float4 ba = *reinterpret_cast<const float4*>(b1 + q * 8);
    float4 bb = *reinterpret_cast<const float4*>(b1 + q * 8 + 4);
    float bias[8] = {ba.x, ba.y, ba.z, ba.w, bb.x, bb.y, bb.z, bb.w};

    unsigned pk[4];
#pragma unroll
    for (int p = 0; p < 4; ++p) {
        float o0 = dv * fmaxf(0.f, fmaf(dv, acc[2 * p] + self[2 * p], bias[2 * p]));
        float o1 = dv * fmaxf(0.f, fmaf(dv, acc[2 * p + 1] + self[2 * p + 1], bias[2 * p + 1]));
        pk[p] = bf16rtn(o0) | (bf16rtn(o1) << 16);
    }
    *reinterpret_cast<uint4*>(hsh + (size_t)v * HID + q * 8) = make_uint4(pk[0], pk[1], pk[2], pk[3]);
}

// ---------------- aggregation 2: s = dv*(sum hs_u + hs_v); out = s @ [Wmu|Wlv] + bias ----------------

__global__ __launch_bounds__(256) void k_agg2(const u16* __restrict__ hsh,
                                              const int* __restrict__ srow,
                                              const int* __restrict__ start,
                                              const int* __restrict__ deg,
                                              const float* __restrict__ dis,
                                              const float* __restrict__ Wmu,
                                              const float* __restrict__ Wlv,
                                              const float* __restrict__ bmu,
                                              const float* __restrict__ blv,
                                              float* __restrict__ out, int n) {
    __shared__ float wcs[32][36];      // [Wmu | Wlv] combined, 16B-aligned rows
    __shared__ float svec[4][16][36];  // per-wave, per-dest aggregated s vector
    int tid = threadIdx.x;
    for (int i = tid; i < 32 * 32; i += 256) {
        int k = i >> 5, c = i & 31;
        wcs[k][c] = (c < OUT_CH) ? Wmu[k * OUT_CH + c] : Wlv[k * OUT_CH + (c - OUT_CH)];
    }

    int lane = tid & 63;
    int g = lane >> 2;
    int q = lane & 3;
    int wv = tid >> 6;
    int v = blockIdx.x * 64 + wv * 16 + g;
    if (v >= n) v = n - 1;
    int s = start[v], d = deg[v];
    float dv = dis[v];

    float acc[8];
#pragma unroll
    for (int c = 0; c < 8; ++c) acc[c] = 0.f;

    for (int i = 0; i < d; i += 4) {
#pragma unroll
        for (int j = 0; j < 4; ++j) {
            int idx = i + j;
            bool valid = idx < d;
            int u = srow[s + (valid ? idx : 0)];
            uint4 gv = *reinterpret_cast<const uint4*>(hsh + (size_t)u * HID + q * 8);
            float m = valid ? 1.f : 0.f;
            acc[0] = fmaf(m, bflo(gv.x), acc[0]);
            acc[1] = fmaf(m, bfhi(gv.x), acc[1]);
            acc[2] = fmaf(m, bflo(gv.y), acc[2]);
            acc[3] = fmaf(m, bfhi(gv.y), acc[3]);
            acc[4] = fmaf(m, bflo(gv.z), acc[4]);
            acc[5] = fmaf(m, bfhi(gv.z), acc[5]);
            acc[6] = fmaf(m, bflo(gv.w), acc[6]);
            acc[7] = fmaf(m, bfhi(gv.w), acc[7]);
        }
    }

    uint4 sv4 = *reinterpret_cast<const uint4*>(hsh + (size_t)v * HID + q * 8);
    float self[8] = {bflo(sv4.x), bfhi(sv4.x), bflo(sv4.y), bfhi(sv4.y),
                     bflo(sv4.z), bfhi(sv4.z), bflo(sv4.w), bfhi(sv4.w)};
#pragma unroll
    for (int c = 0; c < 8; ++c)
        svec[wv][g][q * 8 + c] = dv * (acc[c] + self[c]);
    __syncthreads();

    // epilogue: lane computes out channels [q*8, q*8+8)
    float o[8];
#pragma unroll
    for (int c = 0; c < 8; ++c) o[c] = 0.f;
#pragma unroll
    for (int k = 0; k < 32; ++k) {
        float skv = svec[wv][g][k];
        float4 wa = *reinterpret_cast<const float4*>(&wcs[k][q * 8]);
        float4 wb = *reinterpret_cast<const float4*>(&wcs[k][q * 8 + 4]);
        o[0] = fmaf(skv, wa.x, o[0]);
        o[1] = fmaf(skv, wa.y, o[1]);
        o[2] = fmaf(skv, wa.z, o[2]);
        o[3] = fmaf(skv, wa.w, o[3]);
        o[4] = fmaf(skv, wb.x, o[4]);
        o[5] = fmaf(skv, wb.y, o[5]);
        o[6] = fmaf(skv, wb.z, o[6]);
        o[7] = fmaf(skv, wb.w, o[7]);
    }
    float* dst;
    const float* bsrc;
    if (q < 2) { dst = out + (size_t)v * OUT_CH + q * 8;                      bsrc = bmu + q * 8; }
    else       { dst = out + (size_t)N_NODES * OUT_CH + (size_t)v * OUT_CH + (q - 2) * 8; bsrc = blv + (q - 2) * 8; }
    float4 b0 = *reinterpret_cast<const float4*>(bsrc);
    float4 b1v = *reinterpret_cast<const float4*>(bsrc + 4);
    *reinterpret_cast<float4*>(dst)     = make_float4(o[0] + b0.x, o[1] + b0.y, o[2] + b0.z, o[3] + b0.w);
    *reinterpret_cast<float4*>(dst + 4) = make_float4(o[4] + b1v.x, o[5] + b1v.y, o[6] + b1v.z, o[7] + b1v.w);
}

// ---------------- launch ----------------

extern "C" void kernel_launch(void* const* d_in, const int* in_sizes, int n_in,
                              void* d_out, int out_size, void* d_ws, size_t ws_size,
                              hipStream_t stream) {
    const float* x   = (const float*)d_in[0];
    const int*   ei  = (const int*)d_in[1];
    const float* W1  = (const float*)d_in[2];
    const float* b1  = (const float*)d_in[3];
    const float* Wmu = (const float*)d_in[4];
    const float* bmu = (const float*)d_in[5];
    const float* Wlv = (const float*)d_in[6];
    const float* blv = (const float*)d_in[7];
    float* out = (float*)d_out;

    const int* row = ei;            // edge_index[0]
    const int* col = ei + E_EDGES;  // edge_index[1]

    char* w = (char*)d_ws;
    int*   bcnt   = (int*)w;  w += 1024;
    int*   bstart = (int*)w;  w += 1024;
    int*   bcur   = (int*)w;  w += 1024;
    int*   deg    = (int*)w;  w += (size_t)N_NODES * 4;
    float* dis    = (float*)w; w += (size_t)N_NODES * 4;
    int*   start  = (int*)w;  w += (size_t)N_NODES * 4;
    int*   srow   = (int*)w;  w += (size_t)E_EDGES * 4;
    unsigned* psrc = (unsigned*)w;   // 12.8 MB, aliased with h0sh+hsh (psrc dead after k_bsort)
    u16*   h0sh   = (u16*)w;  w += (size_t)N_NODES * HID * 2;
    u16*   hsh    = (u16*)w;  w += (size_t)N_NODES * HID * 2;

    hipMemsetAsync(bcnt, 0, 1024, stream);

    const int TB = 256;
    k_bcount<<<1024, TB, 0, stream>>>(col, bcnt, E_EDGES);
    k_bscan<<<1, 256, 0, stream>>>(bcnt, bstart, bcur);
    k_part<<<PART_BLOCKS, 256, 0, stream>>>(row, col, bcur, psrc, E_EDGES);
    k_bsort<<<B_BUCKETS, 512, 0, stream>>>(psrc, bstart, srow, deg, start, dis);
    k_gemm1<<<(N_NODES + G1_NODES - 1) / G1_NODES, 256, 0, stream>>>(x, W1, dis, h0sh, N_NODES);
    k_agg1<<<(N_NODES + 63) / 64, TB, 0, stream>>>(h0sh, srow, start, deg, dis, b1, hsh, N_NODES);
    k_agg2<<<(N_NODES + 63) / 64, TB, 0, stream>>>(hsh, srow, start, deg, dis, Wmu, Wlv, bmu, blv, out, N_NODES);
}

// Round 7
// 242.145 us; speedup vs baseline: 1.1812x; 1.1812x over previous
//
#include <hip/hip_runtime.h>

#define N_NODES 100000
#define E_EDGES 3200000
#define IN_CH 256
#define HID 32
#define OUT_CH 16

#define B_BUCKETS 250     // buckets over nodes
#define NPB 400           // nodes per bucket (250*400 = 100000 exactly)
#define CAP 20000         // LDS staging capacity in k_bsort
#define PART_BLOCKS 512
#define PART_CHUNK ((E_EDGES + PART_BLOCKS - 1) / PART_BLOCKS)  // 6250

typedef unsigned short u16;
typedef __attribute__((ext_vector_type(8))) short bf16x8;
typedef __attribute__((ext_vector_type(4))) float f32x4;

__device__ __forceinline__ unsigned bf16rtn(float f) {
    unsigned u = __float_as_uint(f);
    return (u + 0x7FFFu + ((u >> 16) & 1u)) >> 16;   // round-to-nearest-even, finite inputs
}
__device__ __forceinline__ float bflo(unsigned u) { return __uint_as_float(u << 16); }
__device__ __forceinline__ float bfhi(unsigned u) { return __uint_as_float(u & 0xFFFF0000u); }

// ---------------- phase 1: per-bucket edge counts ----------------

__global__ void k_bcount(const int* __restrict__ col, int* __restrict__ bcnt, int e) {
    __shared__ int h[B_BUCKETS];
    for (int i = threadIdx.x; i < B_BUCKETS; i += blockDim.x) h[i] = 0;
    __syncthreads();
    for (int i = blockIdx.x * blockDim.x + threadIdx.x; i < e; i += gridDim.x * blockDim.x)
        atomicAdd(&h[col[i] / NPB], 1);
    __syncthreads();
    for (int i = threadIdx.x; i < B_BUCKETS; i += blockDim.x)
        if (h[i]) atomicAdd(&bcnt[i], h[i]);
}

// ---------------- phase 2: scan bucket counts (1 block) ----------------

__global__ void k_bscan(const int* __restrict__ bcnt, int* __restrict__ bstart,
                        int* __restrict__ bcur) {
    __shared__ int a[256], b[256];
    int t = threadIdx.x;
    int myc = (t < B_BUCKETS) ? bcnt[t] : 0;
    a[t] = myc;
    __syncthreads();
    int* sp = a; int* dp = b;
    for (int off = 1; off < 256; off <<= 1) {
        dp[t] = sp[t] + ((t >= off) ? sp[t - off] : 0);
        __syncthreads();
        int* tm = sp; sp = dp; dp = tm;
    }
    int incl = sp[t];
    int excl = incl - myc;
    if (t < B_BUCKETS) { bstart[t] = excl; bcur[t] = excl; }
    if (t == B_BUCKETS - 1) bstart[B_BUCKETS] = incl;
}

// ---------------- phase 3: partition edges into buckets (LDS-aggregated) ----------------

__global__ __launch_bounds__(256) void k_part(const int* __restrict__ row,
                                              const int* __restrict__ col,
                                              int* __restrict__ bcur,
                                              unsigned* __restrict__ psrc, int e) {
    __shared__ int hist[B_BUCKETS];
    __shared__ int base[B_BUCKETS];
    int lo = blockIdx.x * PART_CHUNK;
    int hi = min(e, lo + PART_CHUNK);
    if (lo >= hi) return;
    for (int i = threadIdx.x; i < B_BUCKETS; i += blockDim.x) hist[i] = 0;
    __syncthreads();
    for (int i = lo + threadIdx.x; i < hi; i += blockDim.x)
        atomicAdd(&hist[col[i] / NPB], 1);
    __syncthreads();
    for (int i = threadIdx.x; i < B_BUCKETS; i += blockDim.x) {
        int h = hist[i];
        base[i] = h ? atomicAdd(&bcur[i], h) : 0;
    }
    __syncthreads();
    for (int i = threadIdx.x; i < B_BUCKETS; i += blockDim.x) hist[i] = 0; // reuse as cursor
    __syncthreads();
    for (int i = lo + threadIdx.x; i < hi; i += blockDim.x) {
        int c = col[i];
        int b = c / NPB;
        int pos = base[b] + atomicAdd(&hist[b], 1);
        psrc[pos] = ((unsigned)(c - b * NPB) << 17) | (unsigned)row[i];
    }
}

// ---------------- phase 4: within-bucket sort in LDS -> srow, deg, start, dis ----------------

__global__ __launch_bounds__(512) void k_bsort(const unsigned* __restrict__ psrc,
                                               const int* __restrict__ bstart,
                                               int* __restrict__ srow, int* __restrict__ deg,
                                               int* __restrict__ start, float* __restrict__ dis) {
    __shared__ unsigned buf[CAP];
    __shared__ int cnt[512];
    __shared__ int sa[512];
    __shared__ int sb[512];
    int b = blockIdx.x, t = threadIdx.x;
    int s0 = bstart[b], s1 = bstart[b + 1], len = s1 - s0;

    cnt[t] = 0;
    __syncthreads();
    for (int i = t; i < len; i += 512)
        atomicAdd(&cnt[psrc[s0 + i] >> 17], 1);
    __syncthreads();

    sa[t] = cnt[t];
    __syncthreads();
    int* sp = sa; int* dp = sb;
    for (int off = 1; off < 512; off <<= 1) {
        dp[t] = sp[t] + ((t >= off) ? sp[t - off] : 0);
        __syncthreads();
        int* tm = sp; sp = dp; dp = tm;
    }
    int ex = sp[t] - cnt[t];
    __syncthreads();
    sa[t] = ex;
    sb[t] = ex;
    if (t < NPB) {
        int node = b * NPB + t;
        int d = cnt[t];
        deg[node] = d;
        start[node] = s0 + ex;
        dis[node] = rsqrtf((float)(d + 1));
    }
    __syncthreads();

    bool fits = (len <= CAP);
    for (int i = t; i < len; i += 512) {
        unsigned p = psrc[s0 + i];
        int cl = (int)(p >> 17);
        int pos = atomicAdd(&sb[cl], 1);
        if (fits) buf[pos] = p & 0x1FFFFu;
        else      srow[s0 + pos] = (int)(p & 0x1FFFFu);
    }
    __syncthreads();
    if (fits)
        for (int i = t; i < len; i += 512)
            srow[s0 + i] = (int)buf[i];
}

// ---------------- W1 -> MFMA B-fragment pack: W1f[kt][ct][lane] (uint4 = 8 bf16) ----------------
// frag element (kt,ct,lane,j) = W1[kt*32 + (lane>>4)*8 + j][ct*16 + (lane&15)]

__global__ void k_wprep(const float* __restrict__ W1, uint4* __restrict__ W1f) {
    int t = threadIdx.x;
    for (int s = t; s < 1024; s += 256) {
        int lane = s & 63;
        int ctkt = s >> 6;          // kt*2 + ct
        int ct = ctkt & 1, kt = ctkt >> 1;
        int colc = ct * 16 + (lane & 15);
        int k0 = kt * 32 + (lane >> 4) * 8;
        unsigned p[4];
#pragma unroll
        for (int pp = 0; pp < 4; ++pp) {
            unsigned lo = bf16rtn(W1[(k0 + 2 * pp) * HID + colc]);
            unsigned hi = bf16rtn(W1[(k0 + 2 * pp + 1) * HID + colc]);
            p[pp] = lo | (hi << 16);
        }
        W1f[s] = make_uint4(p[0], p[1], p[2], p[3]);
    }
}

// ---------------- layer 1 GEMM via MFMA: h0sh = bf16( dis * (x @ W1) ) ----------------
// wave = 16 rows; A-frag from f32 x converted in-register; B preloaded in VGPRs.

__global__ __launch_bounds__(256) void k_gemm1(const float* __restrict__ x,
                                               const uint4* __restrict__ W1f,
                                               const float* __restrict__ dis,
                                               u16* __restrict__ h0sh, int n) {
    int tid = threadIdx.x;
    int lane = tid & 63;
    int wv = tid >> 6;
    int vbase = blockIdx.x * 64 + wv * 16;
    if (vbase >= n) return;                 // N multiple of 16: waves are all-or-nothing
    int arow = lane & 15;
    int kg = lane >> 4;
    const float* xr = x + (size_t)(vbase + arow) * IN_CH + kg * 8;

    uint4 bfrag[8][2];
#pragma unroll
    for (int kt = 0; kt < 8; ++kt) {
#pragma unroll
        for (int ct = 0; ct < 2; ++ct)
            bfrag[kt][ct] = W1f[(kt * 2 + ct) * 64 + lane];
    }

    f32x4 acc0 = {0.f, 0.f, 0.f, 0.f};
    f32x4 acc1 = {0.f, 0.f, 0.f, 0.f};
#pragma unroll
    for (int kt = 0; kt < 8; ++kt) {
        float4 a0 = *reinterpret_cast<const float4*>(xr + kt * 32);
        float4 a1 = *reinterpret_cast<const float4*>(xr + kt * 32 + 4);
        union { unsigned u[4]; bf16x8 v; } af;
        af.u[0] = bf16rtn(a0.x) | (bf16rtn(a0.y) << 16);
        af.u[1] = bf16rtn(a0.z) | (bf16rtn(a0.w) << 16);
        af.u[2] = bf16rtn(a1.x) | (bf16rtn(a1.y) << 16);
        af.u[3] = bf16rtn(a1.z) | (bf16rtn(a1.w) << 16);
        union { uint4 q; bf16x8 v; } b0, b1;
        b0.q = bfrag[kt][0];
        b1.q = bfrag[kt][1];
        acc0 = __builtin_amdgcn_mfma_f32_16x16x32_bf16(af.v, b0.v, acc0, 0, 0, 0);
        acc1 = __builtin_amdgcn_mfma_f32_16x16x32_bf16(af.v, b1.v, acc1, 0, 0, 0);
    }

    int r0 = (lane >> 4) * 4;
    int colo = lane & 15;
#pragma unroll
    for (int r = 0; r < 4; ++r) {
        int v = vbase + r0 + r;
        float dv = dis[v];
        h0sh[(size_t)v * HID + colo]      = (u16)bf16rtn(acc0[r] * dv);
        h0sh[(size_t)v * HID + 16 + colo] = (u16)bf16rtn(acc1[r] * dv);
    }
}

// ---------------- aggregation 1: hsh = bf16( dis * relu(dv*(sum h0s_u + h0s_v) + b1) ) ----------------
// 16 dests/wave, 4 lanes/dest, lane covers 8 channels (16 B bf16 gather), unroll 4.

__global__ __launch_bounds__(256) void k_agg1(const u16* __restrict__ h0sh,
                                              const int* __restrict__ srow,
                                              const int* __restrict__ start,
                                              const int* __restrict__ deg,
                                              const float* __restrict__ dis,
                                              const float* __restrict__ b1,
                                              u16* __restrict__ hsh, int n) {
    int tid = threadIdx.x;
    int lane = tid & 63;
    int g = lane >> 2;          // dest within wave, 0..15
    int q = lane & 3;           // channel-octet, 0..3
    int wv = tid >> 6;
    int v = blockIdx.x * 64 + wv * 16 + g;
    if (v >= n) v = n - 1;
    int s = start[v], d = deg[v];
    float dv = dis[v];

    float acc[8];
#pragma unroll
    for (int c = 0; c < 8; ++c) acc[c] = 0.f;

    for (int i = 0; i < d; i += 4) {
#pragma unroll
        for (int j = 0; j < 4; ++j) {
            int idx = i + j;
            bool valid = idx < d;
            int u = srow[s + (valid ? idx : 0)];
            uint4 gv = *reinterpret_cast<const uint4*>(h0sh + (size_t)u * HID + q * 8);
            float m = valid ? 1.f : 0.f;
            acc[0] = fmaf(m, bflo(gv.x), acc[0]);
            acc[1] = fmaf(m, bfhi(gv.x), acc[1]);
            acc[2] = fmaf(m, bflo(gv.y), acc[2]);
            acc[3] = fmaf(m, bfhi(gv.y), acc[3]);
            acc[4] = fmaf(m, bflo(gv.z), acc[4]);
            acc[5] = fmaf(m, bfhi(gv.z), acc[5]);
            acc[6] = fmaf(m, bflo(gv.w), acc[6]);
            acc[7] = fmaf(m, bfhi(gv.w), acc[7]);
        }
    }

    uint4 sv = *reinterpret_cast<const uint4*>(h0sh + (size_t)v * HID + q * 8);
    float self[8] = {bflo(sv.x), bfhi(sv.x), bflo(sv.y), bfhi(sv.y),
                     bflo(sv.z), bfhi(sv.z), bflo(sv.w), bfhi(sv.w)};
    float4 ba = *reinterpret_cast<const float4*>(b1 + q * 8);
    float4 bb = *reinterpret_cast<const float4*>(b1 + q * 8 + 4);
    float bias[8] = {ba.x, ba.y, ba.z, ba.w, bb.x, bb.y, bb.z, bb.w};

    unsigned pk[4];
#pragma unroll
    for (int p = 0; p < 4; ++p) {
        float o0 = dv * fmaxf(0.f, fmaf(dv, acc[2 * p] + self[2 * p], bias[2 * p]));
        float o1 = dv * fmaxf(0.f, fmaf(dv, acc[2 * p + 1] + self[2 * p + 1], bias[2 * p + 1]));
        pk[p] = bf16rtn(o0) | (bf16rtn(o1) << 16);
    }
    *reinterpret_cast<uint4*>(hsh + (size_t)v * HID + q * 8) = make_uint4(pk[0], pk[1], pk[2], pk[3]);
}

// ---------------- aggregation 2: s = dv*(sum hs_u + hs_v); out = s @ [Wmu|Wlv] + bias ----------------

__global__ __launch_bounds__(256) void k_agg2(const u16* __restrict__ hsh,
                                              const int* __restrict__ srow,
                                              const int* __restrict__ start,
                                              const int* __restrict__ deg,
                                              const float* __restrict__ dis,
                                              const float* __restrict__ Wmu,
                                              const float* __restrict__ Wlv,
                                              const float* __restrict__ bmu,
                                              const float* __restrict__ blv,
                                              float* __restrict__ out, int n) {
    __shared__ float wcs[32][36];      // [Wmu | Wlv] combined, 16B-aligned rows
    __shared__ float svec[4][16][36];  // per-wave, per-dest aggregated s vector
    int tid = threadIdx.x;
    for (int i = tid; i < 32 * 32; i += 256) {
        int k = i >> 5, c = i & 31;
        wcs[k][c] = (c < OUT_CH) ? Wmu[k * OUT_CH + c] : Wlv[k * OUT_CH + (c - OUT_CH)];
    }

    int lane = tid & 63;
    int g = lane >> 2;
    int q = lane & 3;
    int wv = tid >> 6;
    int v = blockIdx.x * 64 + wv * 16 + g;
    if (v >= n) v = n - 1;
    int s = start[v], d = deg[v];
    float dv = dis[v];

    float acc[8];
#pragma unroll
    for (int c = 0; c < 8; ++c) acc[c] = 0.f;

    for (int i = 0; i < d; i += 4) {
#pragma unroll
        for (int j = 0; j < 4; ++j) {
            int idx = i + j;
            bool valid = idx < d;
            int u = srow[s + (valid ? idx : 0)];
            uint4 gv = *reinterpret_cast<const uint4*>(hsh + (size_t)u * HID + q * 8);
            float m = valid ? 1.f : 0.f;
            acc[0] = fmaf(m, bflo(gv.x), acc[0]);
            acc[1] = fmaf(m, bfhi(gv.x), acc[1]);
            acc[2] = fmaf(m, bflo(gv.y), acc[2]);
            acc[3] = fmaf(m, bfhi(gv.y), acc[3]);
            acc[4] = fmaf(m, bflo(gv.z), acc[4]);
            acc[5] = fmaf(m, bfhi(gv.z), acc[5]);
            acc[6] = fmaf(m, bflo(gv.w), acc[6]);
            acc[7] = fmaf(m, bfhi(gv.w), acc[7]);
        }
    }

    uint4 sv4 = *reinterpret_cast<const uint4*>(hsh + (size_t)v * HID + q * 8);
    float self[8] = {bflo(sv4.x), bfhi(sv4.x), bflo(sv4.y), bfhi(sv4.y),
                     bflo(sv4.z), bfhi(sv4.z), bflo(sv4.w), bfhi(sv4.w)};
#pragma unroll
    for (int c = 0; c < 8; ++c)
        svec[wv][g][q * 8 + c] = dv * (acc[c] + self[c]);
    __syncthreads();

    // epilogue: lane computes out channels [q*8, q*8+8)
    float o[8];
#pragma unroll
    for (int c = 0; c < 8; ++c) o[c] = 0.f;
#pragma unroll
    for (int k = 0; k < 32; ++k) {
        float skv = svec[wv][g][k];
        float4 wa = *reinterpret_cast<const float4*>(&wcs[k][q * 8]);
        float4 wb = *reinterpret_cast<const float4*>(&wcs[k][q * 8 + 4]);
        o[0] = fmaf(skv, wa.x, o[0]);
        o[1] = fmaf(skv, wa.y, o[1]);
        o[2] = fmaf(skv, wa.z, o[2]);
        o[3] = fmaf(skv, wa.w, o[3]);
        o[4] = fmaf(skv, wb.x, o[4]);
        o[5] = fmaf(skv, wb.y, o[5]);
        o[6] = fmaf(skv, wb.z, o[6]);
        o[7] = fmaf(skv, wb.w, o[7]);
    }
    float* dst;
    const float* bsrc;
    if (q < 2) { dst = out + (size_t)v * OUT_CH + q * 8;                      bsrc = bmu + q * 8; }
    else       { dst = out + (size_t)N_NODES * OUT_CH + (size_t)v * OUT_CH + (q - 2) * 8; bsrc = blv + (q - 2) * 8; }
    float4 b0 = *reinterpret_cast<const float4*>(bsrc);
    float4 b1v = *reinterpret_cast<const float4*>(bsrc + 4);
    *reinterpret_cast<float4*>(dst)     = make_float4(o[0] + b0.x, o[1] + b0.y, o[2] + b0.z, o[3] + b0.w);
    *reinterpret_cast<float4*>(dst + 4) = make_float4(o[4] + b1v.x, o[5] + b1v.y, o[6] + b1v.z, o[7] + b1v.w);
}

// ---------------- launch ----------------

extern "C" void kernel_launch(void* const* d_in, const int* in_sizes, int n_in,
                              void* d_out, int out_size, void* d_ws, size_t ws_size,
                              hipStream_t stream) {
    const float* x   = (const float*)d_in[0];
    const int*   ei  = (const int*)d_in[1];
    const float* W1  = (const float*)d_in[2];
    const float* b1  = (const float*)d_in[3];
    const float* Wmu = (const float*)d_in[4];
    const float* bmu = (const float*)d_in[5];
    const float* Wlv = (const float*)d_in[6];
    const float* blv = (const float*)d_in[7];
    float* out = (float*)d_out;

    const int* row = ei;            // edge_index[0]
    const int* col = ei + E_EDGES;  // edge_index[1]

    char* w = (char*)d_ws;
    int*   bcnt   = (int*)w;  w += 1024;
    int*   bstart = (int*)w;  w += 1024;
    int*   bcur   = (int*)w;  w += 1024;
    uint4* W1f    = (uint4*)w; w += 16384;   // 1024 * 16B fragments
    int*   deg    = (int*)w;  w += (size_t)N_NODES * 4;
    float* dis    = (float*)w; w += (size_t)N_NODES * 4;
    int*   start  = (int*)w;  w += (size_t)N_NODES * 4;
    int*   srow   = (int*)w;  w += (size_t)E_EDGES * 4;
    unsigned* psrc = (unsigned*)w;   // 12.8 MB, aliased with h0sh+hsh (psrc dead after k_bsort)
    u16*   h0sh   = (u16*)w;  w += (size_t)N_NODES * HID * 2;
    u16*   hsh    = (u16*)w;  w += (size_t)N_NODES * HID * 2;

    hipMemsetAsync(bcnt, 0, 1024, stream);

    const int TB = 256;
    k_bcount<<<1024, TB, 0, stream>>>(col, bcnt, E_EDGES);
    k_bscan<<<1, 256, 0, stream>>>(bcnt, bstart, bcur);
    k_part<<<PART_BLOCKS, 256, 0, stream>>>(row, col, bcur, psrc, E_EDGES);
    k_wprep<<<1, 256, 0, stream>>>(W1, W1f);
    k_bsort<<<B_BUCKETS, 512, 0, stream>>>(psrc, bstart, srow, deg, start, dis);
    k_gemm1<<<(N_NODES + 63) / 64, 256, 0, stream>>>(x, W1f, dis, h0sh, N_NODES);
    k_agg1<<<(N_NODES + 63) / 64, TB, 0, stream>>>(h0sh, srow, start, deg, dis, b1, hsh, N_NODES);
    k_agg2<<<(N_NODES + 63) / 64, TB, 0, stream>>>(hsh, srow, start, deg, dis, Wmu, Wlv, bmu, blv, out, N_NODES);
}

// Round 8
// 224.231 us; speedup vs baseline: 1.2755x; 1.0799x over previous
//
#include <hip/hip_runtime.h>

#define N_NODES 100000
#define E_EDGES 3200000
#define IN_CH 256
#define HID 32
#define OUT_CH 16

#define B_BUCKETS 250     // buckets over nodes
#define NPB 400           // nodes per bucket (250*400 = 100000 exactly)
#define CAP 20000         // LDS staging capacity in k_bsort
#define PART_BLOCKS 512
#define PART_CHUNK ((E_EDGES + PART_BLOCKS - 1) / PART_BLOCKS)  // 6250

typedef unsigned short u16;
typedef __attribute__((ext_vector_type(8))) short bf16x8;
typedef __attribute__((ext_vector_type(4))) float f32x4;

__device__ __forceinline__ unsigned bf16rtn(float f) {
    unsigned u = __float_as_uint(f);
    return (u + 0x7FFFu + ((u >> 16) & 1u)) >> 16;   // round-to-nearest-even, finite inputs
}
__device__ __forceinline__ float bflo(unsigned u) { return __uint_as_float(u << 16); }
__device__ __forceinline__ float bfhi(unsigned u) { return __uint_as_float(u & 0xFFFF0000u); }

// ---------------- phase 1: per-bucket edge counts ----------------

__global__ void k_bcount(const int* __restrict__ col, int* __restrict__ bcnt, int e) {
    __shared__ int h[B_BUCKETS];
    for (int i = threadIdx.x; i < B_BUCKETS; i += blockDim.x) h[i] = 0;
    __syncthreads();
    for (int i = blockIdx.x * blockDim.x + threadIdx.x; i < e; i += gridDim.x * blockDim.x)
        atomicAdd(&h[col[i] / NPB], 1);
    __syncthreads();
    for (int i = threadIdx.x; i < B_BUCKETS; i += blockDim.x)
        if (h[i]) atomicAdd(&bcnt[i], h[i]);
}

// ---------------- phase 2: scan bucket counts (1 block) ----------------

__global__ void k_bscan(const int* __restrict__ bcnt, int* __restrict__ bstart,
                        int* __restrict__ bcur) {
    __shared__ int a[256], b[256];
    int t = threadIdx.x;
    int myc = (t < B_BUCKETS) ? bcnt[t] : 0;
    a[t] = myc;
    __syncthreads();
    int* sp = a; int* dp = b;
    for (int off = 1; off < 256; off <<= 1) {
        dp[t] = sp[t] + ((t >= off) ? sp[t - off] : 0);
        __syncthreads();
        int* tm = sp; sp = dp; dp = tm;
    }
    int incl = sp[t];
    int excl = incl - myc;
    if (t < B_BUCKETS) { bstart[t] = excl; bcur[t] = excl; }
    if (t == B_BUCKETS - 1) bstart[B_BUCKETS] = incl;
}

// ---------------- phase 3: partition edges into buckets (LDS-aggregated) ----------------

__global__ __launch_bounds__(256) void k_part(const int* __restrict__ row,
                                              const int* __restrict__ col,
                                              int* __restrict__ bcur,
                                              unsigned* __restrict__ psrc, int e) {
    __shared__ int hist[B_BUCKETS];
    __shared__ int base[B_BUCKETS];
    int lo = blockIdx.x * PART_CHUNK;
    int hi = min(e, lo + PART_CHUNK);
    if (lo >= hi) return;
    for (int i = threadIdx.x; i < B_BUCKETS; i += blockDim.x) hist[i] = 0;
    __syncthreads();
    for (int i = lo + threadIdx.x; i < hi; i += blockDim.x)
        atomicAdd(&hist[col[i] / NPB], 1);
    __syncthreads();
    for (int i = threadIdx.x; i < B_BUCKETS; i += blockDim.x) {
        int h = hist[i];
        base[i] = h ? atomicAdd(&bcur[i], h) : 0;
    }
    __syncthreads();
    for (int i = threadIdx.x; i < B_BUCKETS; i += blockDim.x) hist[i] = 0; // reuse as cursor
    __syncthreads();
    for (int i = lo + threadIdx.x; i < hi; i += blockDim.x) {
        int c = col[i];
        int b = c / NPB;
        int pos = base[b] + atomicAdd(&hist[b], 1);
        psrc[pos] = ((unsigned)(c - b * NPB) << 17) | (unsigned)row[i];
    }
}

// ---------------- phase 4: within-bucket sort in LDS -> srow, deg, start, dis ----------------

__global__ __launch_bounds__(512) void k_bsort(const unsigned* __restrict__ psrc,
                                               const int* __restrict__ bstart,
                                               int* __restrict__ srow, int* __restrict__ deg,
                                               int* __restrict__ start, float* __restrict__ dis) {
    __shared__ unsigned buf[CAP];
    __shared__ int cnt[512];
    __shared__ int sa[512];
    __shared__ int sb[512];
    int b = blockIdx.x, t = threadIdx.x;
    int s0 = bstart[b], s1 = bstart[b + 1], len = s1 - s0;

    cnt[t] = 0;
    __syncthreads();
    for (int i = t; i < len; i += 512)
        atomicAdd(&cnt[psrc[s0 + i] >> 17], 1);
    __syncthreads();

    sa[t] = cnt[t];
    __syncthreads();
    int* sp = sa; int* dp = sb;
    for (int off = 1; off < 512; off <<= 1) {
        dp[t] = sp[t] + ((t >= off) ? sp[t - off] : 0);
        __syncthreads();
        int* tm = sp; sp = dp; dp = tm;
    }
    int ex = sp[t] - cnt[t];
    __syncthreads();
    sa[t] = ex;
    sb[t] = ex;
    if (t < NPB) {
        int node = b * NPB + t;
        int d = cnt[t];
        deg[node] = d;
        start[node] = s0 + ex;
        dis[node] = rsqrtf((float)(d + 1));
    }
    __syncthreads();

    bool fits = (len <= CAP);
    for (int i = t; i < len; i += 512) {
        unsigned p = psrc[s0 + i];
        int cl = (int)(p >> 17);
        int pos = atomicAdd(&sb[cl], 1);
        if (fits) buf[pos] = p & 0x1FFFFu;
        else      srow[s0 + pos] = (int)(p & 0x1FFFFu);
    }
    __syncthreads();
    if (fits)
        for (int i = t; i < len; i += 512)
            srow[s0 + i] = (int)buf[i];
}

// ---------------- W1 -> MFMA B-fragment pack: W1f[kt][ct][lane] (uint4 = 8 bf16) ----------------

__global__ void k_wprep(const float* __restrict__ W1, uint4* __restrict__ W1f) {
    int t = threadIdx.x;
    for (int s = t; s < 1024; s += 256) {
        int lane = s & 63;
        int ctkt = s >> 6;          // kt*2 + ct
        int ct = ctkt & 1, kt = ctkt >> 1;
        int colc = ct * 16 + (lane & 15);
        int k0 = kt * 32 + (lane >> 4) * 8;
        unsigned p[4];
#pragma unroll
        for (int pp = 0; pp < 4; ++pp) {
            unsigned lo = bf16rtn(W1[(k0 + 2 * pp) * HID + colc]);
            unsigned hi = bf16rtn(W1[(k0 + 2 * pp + 1) * HID + colc]);
            p[pp] = lo | (hi << 16);
        }
        W1f[s] = make_uint4(p[0], p[1], p[2], p[3]);
    }
}

// ---------------- layer 1 GEMM via MFMA: h0sh = bf16( dis * (x @ W1) ) ----------------

__global__ __launch_bounds__(256) void k_gemm1(const float* __restrict__ x,
                                               const uint4* __restrict__ W1f,
                                               const float* __restrict__ dis,
                                               u16* __restrict__ h0sh, int n) {
    int tid = threadIdx.x;
    int lane = tid & 63;
    int wv = tid >> 6;
    int vbase = blockIdx.x * 64 + wv * 16;
    if (vbase >= n) return;                 // N multiple of 16: waves are all-or-nothing
    int arow = lane & 15;
    int kg = lane >> 4;
    const float* xr = x + (size_t)(vbase + arow) * IN_CH + kg * 8;

    uint4 bfrag[8][2];
#pragma unroll
    for (int kt = 0; kt < 8; ++kt) {
#pragma unroll
        for (int ct = 0; ct < 2; ++ct)
            bfrag[kt][ct] = W1f[(kt * 2 + ct) * 64 + lane];
    }

    f32x4 acc0 = {0.f, 0.f, 0.f, 0.f};
    f32x4 acc1 = {0.f, 0.f, 0.f, 0.f};
#pragma unroll
    for (int kt = 0; kt < 8; ++kt) {
        float4 a0 = *reinterpret_cast<const float4*>(xr + kt * 32);
        float4 a1 = *reinterpret_cast<const float4*>(xr + kt * 32 + 4);
        union { unsigned u[4]; bf16x8 v; } af;
        af.u[0] = bf16rtn(a0.x) | (bf16rtn(a0.y) << 16);
        af.u[1] = bf16rtn(a0.z) | (bf16rtn(a0.w) << 16);
        af.u[2] = bf16rtn(a1.x) | (bf16rtn(a1.y) << 16);
        af.u[3] = bf16rtn(a1.z) | (bf16rtn(a1.w) << 16);
        union { uint4 q; bf16x8 v; } b0, b1;
        b0.q = bfrag[kt][0];
        b1.q = bfrag[kt][1];
        acc0 = __builtin_amdgcn_mfma_f32_16x16x32_bf16(af.v, b0.v, acc0, 0, 0, 0);
        acc1 = __builtin_amdgcn_mfma_f32_16x16x32_bf16(af.v, b1.v, acc1, 0, 0, 0);
    }

    int r0 = (lane >> 4) * 4;
    int colo = lane & 15;
#pragma unroll
    for (int r = 0; r < 4; ++r) {
        int v = vbase + r0 + r;
        float dv = dis[v];
        h0sh[(size_t)v * HID + colo]      = (u16)bf16rtn(acc0[r] * dv);
        h0sh[(size_t)v * HID + 16 + colo] = (u16)bf16rtn(acc1[r] * dv);
    }
}

// ---------------- aggregation 1: hsh = bf16( dis * relu(dv*(sum h0s_u + h0s_v) + b1) ) ----------------
// 16 dests/wave, 4 lanes/dest, lane covers 8 channels (16 B bf16 gather), unroll 4.

__global__ __launch_bounds__(256, 6) void k_agg1(const u16* __restrict__ h0sh,
                                                 const int* __restrict__ srow,
                                                 const int* __restrict__ start,
                                                 const int* __restrict__ deg,
                                                 const float* __restrict__ dis,
                                                 const float* __restrict__ b1,
                                                 u16* __restrict__ hsh, int n) {
    int tid = threadIdx.x;
    int lane = tid & 63;
    int g = lane >> 2;          // dest within wave, 0..15
    int q = lane & 3;           // channel-octet, 0..3
    int wv = tid >> 6;
    int v = blockIdx.x * 64 + wv * 16 + g;
    if (v >= n) v = n - 1;
    int s = start[v], d = deg[v];
    float dv = dis[v];

    float acc[8];
#pragma unroll
    for (int c = 0; c < 8; ++c) acc[c] = 0.f;

    for (int i = 0; i < d; i += 4) {
#pragma unroll
        for (int j = 0; j < 4; ++j) {
            int idx = i + j;
            bool valid = idx < d;
            int u = srow[s + (valid ? idx : 0)];
            uint4 gv = *reinterpret_cast<const uint4*>(h0sh + (size_t)u * HID + q * 8);
            float m = valid ? 1.f : 0.f;
            acc[0] = fmaf(m, bflo(gv.x), acc[0]);
            acc[1] = fmaf(m, bfhi(gv.x), acc[1]);
            acc[2] = fmaf(m, bflo(gv.y), acc[2]);
            acc[3] = fmaf(m, bfhi(gv.y), acc[3]);
            acc[4] = fmaf(m, bflo(gv.z), acc[4]);
            acc[5] = fmaf(m, bfhi(gv.z), acc[5]);
            acc[6] = fmaf(m, bflo(gv.w), acc[6]);
            acc[7] = fmaf(m, bfhi(gv.w), acc[7]);
        }
    }

    uint4 sv = *reinterpret_cast<const uint4*>(h0sh + (size_t)v * HID + q * 8);
    float self[8] = {bflo(sv.x), bfhi(sv.x), bflo(sv.y), bfhi(sv.y),
                     bflo(sv.z), bfhi(sv.z), bflo(sv.w), bfhi(sv.w)};
    float4 ba = *reinterpret_cast<const float4*>(b1 + q * 8);
    float4 bb = *reinterpret_cast<const float4*>(b1 + q * 8 + 4);
    float bias[8] = {ba.x, ba.y, ba.z, ba.w, bb.x, bb.y, bb.z, bb.w};

    unsigned pk[4];
#pragma unroll
    for (int p = 0; p < 4; ++p) {
        float o0 = dv * fmaxf(0.f, fmaf(dv, acc[2 * p] + self[2 * p], bias[2 * p]));
        float o1 = dv * fmaxf(0.f, fmaf(dv, acc[2 * p + 1] + self[2 * p + 1], bias[2 * p + 1]));
        pk[p] = bf16rtn(o0) | (bf16rtn(o1) << 16);
    }
    *reinterpret_cast<uint4*>(hsh + (size_t)v * HID + q * 8) = make_uint4(pk[0], pk[1], pk[2], pk[3]);
}

// ---------------- aggregation 2: sf = dv*(sum hs_u + hs_v)  (f32, no epilogue) ----------------

__global__ __launch_bounds__(256, 6) void k_agg2(const u16* __restrict__ hsh,
                                                 const int* __restrict__ srow,
                                                 const int* __restrict__ start,
                                                 const int* __restrict__ deg,
                                                 const float* __restrict__ dis,
                                                 float* __restrict__ sf, int n) {
    int tid = threadIdx.x;
    int lane = tid & 63;
    int g = lane >> 2;
    int q = lane & 3;
    int wv = tid >> 6;
    int v = blockIdx.x * 64 + wv * 16 + g;
    if (v >= n) v = n - 1;
    int s = start[v], d = deg[v];
    float dv = dis[v];

    float acc[8];
#pragma unroll
    for (int c = 0; c < 8; ++c) acc[c] = 0.f;

    for (int i = 0; i < d; i += 4) {
#pragma unroll
        for (int j = 0; j < 4; ++j) {
            int idx = i + j;
            bool valid = idx < d;
            int u = srow[s + (valid ? idx : 0)];
            uint4 gv = *reinterpret_cast<const uint4*>(hsh + (size_t)u * HID + q * 8);
            float m = valid ? 1.f : 0.f;
            acc[0] = fmaf(m, bflo(gv.x), acc[0]);
            acc[1] = fmaf(m, bfhi(gv.x), acc[1]);
            acc[2] = fmaf(m, bflo(gv.y), acc[2]);
            acc[3] = fmaf(m, bfhi(gv.y), acc[3]);
            acc[4] = fmaf(m, bflo(gv.z), acc[4]);
            acc[5] = fmaf(m, bfhi(gv.z), acc[5]);
            acc[6] = fmaf(m, bflo(gv.w), acc[6]);
            acc[7] = fmaf(m, bfhi(gv.w), acc[7]);
        }
    }

    uint4 sv4 = *reinterpret_cast<const uint4*>(hsh + (size_t)v * HID + q * 8);
    float self[8] = {bflo(sv4.x), bfhi(sv4.x), bflo(sv4.y), bfhi(sv4.y),
                     bflo(sv4.z), bfhi(sv4.z), bflo(sv4.w), bfhi(sv4.w)};
    float* dst = sf + (size_t)v * HID + q * 8;
    *reinterpret_cast<float4*>(dst) =
        make_float4(dv * (acc[0] + self[0]), dv * (acc[1] + self[1]),
                    dv * (acc[2] + self[2]), dv * (acc[3] + self[3]));
    *reinterpret_cast<float4*>(dst + 4) =
        make_float4(dv * (acc[4] + self[4]), dv * (acc[5] + self[5]),
                    dv * (acc[6] + self[6]), dv * (acc[7] + self[7]));
}

// ---------------- output transform: out = sf @ [Wmu|Wlv] + bias ----------------
// 8 nodes/block; LDS-staged sf rows + weights; thread = (node, out-channel).

__global__ __launch_bounds__(256) void k_out(const float* __restrict__ sf,
                                             const float* __restrict__ Wmu,
                                             const float* __restrict__ Wlv,
                                             const float* __restrict__ bmu,
                                             const float* __restrict__ blv,
                                             float* __restrict__ out, int n) {
    __shared__ float wc[32][33];
    __shared__ float sbuf[8][33];
    int tid = threadIdx.x;
    for (int i = tid; i < 32 * 32; i += 256) {
        int k = i >> 5, c = i & 31;
        wc[k][c] = (c < OUT_CH) ? Wmu[k * OUT_CH + c] : Wlv[k * OUT_CH + (c - OUT_CH)];
    }
    int vbase = blockIdx.x * 8;
    {   // coalesced row stage: thread t loads element t of the 256-float tile
        int gg = tid >> 5, kk = tid & 31;
        int vsrc = vbase + gg; if (vsrc >= n) vsrc = n - 1;
        sbuf[gg][kk] = sf[(size_t)vsrc * HID + kk];
    }
    __syncthreads();

    int g = tid >> 5, c = tid & 31;
    int v = vbase + g;
    if (v >= n) return;
    float o = 0.f;
#pragma unroll
    for (int k = 0; k < 32; ++k)
        o = fmaf(sbuf[g][k], wc[k][c], o);
    if (c < OUT_CH)
        out[(size_t)v * OUT_CH + c] = o + bmu[c];
    else
        out[(size_t)N_NODES * OUT_CH + (size_t)v * OUT_CH + (c - OUT_CH)] = o + blv[c - OUT_CH];
}

// ---------------- launch ----------------

extern "C" void kernel_launch(void* const* d_in, const int* in_sizes, int n_in,
                              void* d_out, int out_size, void* d_ws, size_t ws_size,
                              hipStream_t stream) {
    const float* x   = (const float*)d_in[0];
    const int*   ei  = (const int*)d_in[1];
    const float* W1  = (const float*)d_in[2];
    const float* b1  = (const float*)d_in[3];
    const float* Wmu = (const float*)d_in[4];
    const float* bmu = (const float*)d_in[5];
    const float* Wlv = (const float*)d_in[6];
    const float* blv = (const float*)d_in[7];
    float* out = (float*)d_out;

    const int* row = ei;            // edge_index[0]
    const int* col = ei + E_EDGES;  // edge_index[1]

    char* w = (char*)d_ws;
    int*   bcnt   = (int*)w;  w += 1024;
    int*   bstart = (int*)w;  w += 1024;
    int*   bcur   = (int*)w;  w += 1024;
    uint4* W1f    = (uint4*)w; w += 16384;   // 1024 * 16B fragments
    int*   deg    = (int*)w;  w += (size_t)N_NODES * 4;
    float* dis    = (float*)w; w += (size_t)N_NODES * 4;
    int*   start  = (int*)w;  w += (size_t)N_NODES * 4;
    int*   srow   = (int*)w;  w += (size_t)E_EDGES * 4;
    unsigned* psrc = (unsigned*)w;   // 12.8 MB, aliased with h0sh+hsh (psrc dead after k_bsort)
    u16*   h0sh   = (u16*)w;  w += (size_t)N_NODES * HID * 2;
    u16*   hsh    = (u16*)w;  w += (size_t)N_NODES * HID * 2;
    float* sf     = (float*)w; w += (size_t)N_NODES * HID * 4;

    hipMemsetAsync(bcnt, 0, 1024, stream);

    const int TB = 256;
    k_bcount<<<1024, TB, 0, stream>>>(col, bcnt, E_EDGES);
    k_bscan<<<1, 256, 0, stream>>>(bcnt, bstart, bcur);
    k_part<<<PART_BLOCKS, 256, 0, stream>>>(row, col, bcur, psrc, E_EDGES);
    k_wprep<<<1, 256, 0, stream>>>(W1, W1f);
    k_bsort<<<B_BUCKETS, 512, 0, stream>>>(psrc, bstart, srow, deg, start, dis);
    k_gemm1<<<(N_NODES + 63) / 64, 256, 0, stream>>>(x, W1f, dis, h0sh, N_NODES);
    k_agg1<<<(N_NODES + 63) / 64, TB, 0, stream>>>(h0sh, srow, start, deg, dis, b1, hsh, N_NODES);
    k_agg2<<<(N_NODES + 63) / 64, TB, 0, stream>>>(hsh, srow, start, deg, dis, sf, N_NODES);
    k_out<<<(N_NODES + 7) / 8, TB, 0, stream>>>(sf, Wmu, Wlv, bmu, blv, out, N_NODES);
}